// Round 2
// baseline (163.216 us; speedup 1.0000x reference)
//
#include <hip/hip_runtime.h>

typedef _Float16 f16;
typedef _Float16 f16x8 __attribute__((ext_vector_type(8)));
typedef float f32x4 __attribute__((ext_vector_type(4)));

#define LOG2E 1.44269504088896f
#define MFMA16(a, b, c) __builtin_amdgcn_mfma_f32_16x16x32_f16(a, b, c, 0, 0, 0)

static __device__ inline f16x8 f16x8_zero() {
    f16x8 v;
#pragma unroll
    for (int i = 0; i < 8; ++i) v[i] = (f16)0.f;
    return v;
}

// ---------------- Kernel 1: projections ----------------
// x: [B,4096,64] f32.  Outputs: fO [B*4096][8] f16, gO [B*4096][8] f16 (pre-scaled by log2e),
// hT [B][64][4096] f16 (transposed so PV MFMA reads contiguous keys).
__global__ __launch_bounds__(256) void proj_kernel(
    const float* __restrict__ x, const float* __restrict__ Kf,
    const float* __restrict__ Kg, const float* __restrict__ Kh,
    const float* __restrict__ bf, const float* __restrict__ bg,
    const float* __restrict__ bh,
    f16* __restrict__ fO, f16* __restrict__ gO, f16* __restrict__ hT)
{
    __shared__ float KT[80 * 64];   // KT[c][d]: c<8 -> f, 8..15 -> g (scaled), 16..79 -> h
    __shared__ float bias[80];
    const int tid = threadIdx.x;

    for (int i = tid; i < 512; i += 256) {          // Kf/Kg are [64][8]
        int d = i >> 3, j = i & 7;
        KT[j * 64 + d] = Kf[i];
        KT[(8 + j) * 64 + d] = Kg[i] * LOG2E;
    }
    for (int i = tid; i < 4096; i += 256) {         // Kh is [64][64]
        int d = i >> 6, c = i & 63;
        KT[(16 + c) * 64 + d] = Kh[i];
    }
    if (tid < 8) { bias[tid] = bf[tid]; bias[8 + tid] = bg[tid] * LOG2E; }
    if (tid >= 16 && tid < 80) bias[tid] = bh[tid - 16];
    __syncthreads();

    const int quarter = tid >> 6;                   // wave id: which 20 output channels
    const int px = blockIdx.x * 64 + (tid & 63);    // pixel (b*4096 + n)
    const float4* xp = (const float4*)(x + (size_t)px * 64);
    float4 xr[16];
#pragma unroll
    for (int i = 0; i < 16; ++i) xr[i] = xp[i];

    float res[20];
    const int c0 = quarter * 20;
#pragma unroll
    for (int cc = 0; cc < 20; ++cc) {
        const int c = c0 + cc;
        float acc = bias[c];
        const float4* wv = (const float4*)(KT + c * 64);
#pragma unroll
        for (int i = 0; i < 16; ++i) {
            float4 w = wv[i];
            acc = fmaf(xr[i].x, w.x, acc);
            acc = fmaf(xr[i].y, w.y, acc);
            acc = fmaf(xr[i].z, w.z, acc);
            acc = fmaf(xr[i].w, w.w, acc);
        }
        res[cc] = acc;
    }

    const int b = px >> 12, n = px & 4095;
    if (quarter == 0) {
        f16x8 fv, gv;
#pragma unroll
        for (int j = 0; j < 8; ++j) { fv[j] = (f16)res[j]; gv[j] = (f16)res[8 + j]; }
        *(f16x8*)(fO + (size_t)px * 8) = fv;
        *(f16x8*)(gO + (size_t)px * 8) = gv;
#pragma unroll
        for (int cc = 16; cc < 20; ++cc)
            hT[(size_t)b * 262144 + (size_t)(cc - 16) * 4096 + n] = (f16)res[cc];
    } else {
#pragma unroll
        for (int cc = 0; cc < 20; ++cc)
            hT[(size_t)b * 262144 + (size_t)(c0 + cc - 16) * 4096 + n] = (f16)res[cc];
    }
}

// ---------------- Kernel 2: flash attention (split-K, barrier-free) ----------------
// NSPLIT blocks per 64-q tile, each covering 4096/NSPLIT keys. 4 waves x 16 q-rows.
// No LDS staging: h^T / f MFMA fragments load directly from global (L2-resident;
// b = blockIdx&7 keeps one batch per XCD). Only LDS use is the per-wave p-transpose.
// Swapped QK^T (S^T = F G^T) so q = lane&15; PV computes O^T = H^T P^T.
// l is accumulated by an extra ones-row MFMA. Defer-max: rescale only when the
// tile max exceeds the running max by >8 (p <= 2^8, safe in f16).
template<int NSPLIT>
__global__ __launch_bounds__(256, 4) void attn2_kernel(
    const f16* __restrict__ fO, const f16* __restrict__ gO,
    const f16* __restrict__ hT, const float* __restrict__ x,
    const float* __restrict__ gamma, float* __restrict__ out,
    float* __restrict__ po, float* __restrict__ pml)
{
    __shared__ __align__(16) unsigned int pbuf[4][2][320];   // per-wave, stride 20 dwords

    const int tid  = threadIdx.x;
    const int w    = tid >> 6;
    const int lane = tid & 63;
    const int lrow = lane & 15;
    const int grp  = lane >> 4;

    const int b  = blockIdx.x & 7;
    const int kc = (NSPLIT == 2) ? ((blockIdx.x >> 3) & 1) : 0;
    const int qt = blockIdx.x >> ((NSPLIT == 2) ? 4 : 3);

    const int KEYS = 4096 / NSPLIT;
    const int NIT  = KEYS / 64;
    const int k0   = kc * KEYS;
    const int qrow = qt * 64 + w * 16 + lrow;     // this lane's query row

    const f16* fb = fO + (size_t)b * 32768;
    const f16* hb = hT + (size_t)b * 262144;

    // B operand of QK: lanes<16 hold g[q][0..7], rest zero (K padded 8->32).
    // A-operand garbage at k>=8 is killed by these zeros, so f loads are unguarded.
    f16x8 gfrag = f16x8_zero();
    if (lane < 16) gfrag = *(const f16x8*)(gO + (size_t)b * 32768 + (size_t)qrow * 8);

    f16x8 ones;
#pragma unroll
    for (int i = 0; i < 8; ++i) ones[i] = (f16)1.f;

    f32x4 acc[4], accl;
#pragma unroll
    for (int cb = 0; cb < 4; ++cb)
#pragma unroll
        for (int r = 0; r < 4; ++r) acc[cb][r] = 0.f;
#pragma unroll
    for (int r = 0; r < 4; ++r) accl[r] = 0.f;

    const f16* hp0 = hb + (size_t)lrow * 4096 + k0 + grp * 8;  // + cb*65536 + t*64 (+32)
    const f16* fp  = fb + (size_t)(k0 + lrow) * 8;             // + t*512 + i*128

    float mrun = -1e30f;

    f16x8 faN[4];
#pragma unroll
    for (int i = 0; i < 4; ++i) faN[i] = *(const f16x8*)(fp + i * 128);

    for (int t = 0; t < NIT; ++t) {
        f16x8 fa[4];
#pragma unroll
        for (int i = 0; i < 4; ++i) fa[i] = faN[i];

        const f16* hpt = hp0 + t * 64;
        f16x8 haA[4];                               // issued early; softmax covers latency
#pragma unroll
        for (int cb = 0; cb < 4; ++cb) haA[cb] = *(const f16x8*)(hpt + cb * 65536);

        if (t + 1 < NIT) {                          // software-pipeline f fragments
            const f16* fpn = fp + (t + 1) * 512;
#pragma unroll
            for (int i = 0; i < 4; ++i) faN[i] = *(const f16x8*)(fpn + i * 128);
        }

        // ---- QK^T: S^T[key][q], keys t*64 + i*16 + grp*4 + r, q = lrow ----
        f32x4 zc; zc[0] = zc[1] = zc[2] = zc[3] = 0.f;
        f32x4 s0 = MFMA16(fa[0], gfrag, zc);
        f32x4 s1 = MFMA16(fa[1], gfrag, zc);
        f32x4 s2 = MFMA16(fa[2], gfrag, zc);
        f32x4 s3 = MFMA16(fa[3], gfrag, zc);

        // ---- online softmax (log2 units) ----
        float m8 = fmaxf(
            fmaxf(fmaxf(fmaxf(s0[0], s0[1]), fmaxf(s0[2], s0[3])),
                  fmaxf(fmaxf(s1[0], s1[1]), fmaxf(s1[2], s1[3]))),
            fmaxf(fmaxf(fmaxf(s2[0], s2[1]), fmaxf(s2[2], s2[3])),
                  fmaxf(fmaxf(s3[0], s3[1]), fmaxf(s3[2], s3[3]))));
        m8 = fmaxf(m8, __shfl_xor(m8, 16));
        m8 = fmaxf(m8, __shfl_xor(m8, 32));

        if (__any(m8 > mrun + 8.f)) {               // defer-max (T13)
            const float mnew = fmaxf(mrun, m8);
            const float sc = exp2f(mrun - mnew);
            mrun = mnew;
#pragma unroll
            for (int cb = 0; cb < 4; ++cb)
#pragma unroll
                for (int r = 0; r < 4; ++r) acc[cb][r] *= sc;
#pragma unroll
            for (int r = 0; r < 4; ++r) accl[r] *= sc;
        }

        f32x4 p0, p1, p2, p3;
#pragma unroll
        for (int r = 0; r < 4; ++r) {
            p0[r] = exp2f(s0[r] - mrun);
            p1[r] = exp2f(s1[r] - mrun);
            p2[r] = exp2f(s2[r] - mrun);
            p3[r] = exp2f(s3[r] - mrun);
        }

        f16x8 haB[4];                               // second key half; pack covers latency
#pragma unroll
        for (int cb = 0; cb < 4; ++cb) haB[cb] = *(const f16x8*)(hpt + cb * 65536 + 32);

        // ---- pack p -> f16, per-wave LDS transpose ----
        unsigned int* pwA = &pbuf[w][0][lrow * 20 + 2 * grp];
        unsigned int* pwB = &pbuf[w][1][lrow * 20 + 2 * grp];
        uint2 A0, A1, B0, B1;
        A0.x = __builtin_bit_cast(unsigned int, __builtin_amdgcn_cvt_pkrtz(p0[0], p0[1]));
        A0.y = __builtin_bit_cast(unsigned int, __builtin_amdgcn_cvt_pkrtz(p0[2], p0[3]));
        A1.x = __builtin_bit_cast(unsigned int, __builtin_amdgcn_cvt_pkrtz(p1[0], p1[1]));
        A1.y = __builtin_bit_cast(unsigned int, __builtin_amdgcn_cvt_pkrtz(p1[2], p1[3]));
        B0.x = __builtin_bit_cast(unsigned int, __builtin_amdgcn_cvt_pkrtz(p2[0], p2[1]));
        B0.y = __builtin_bit_cast(unsigned int, __builtin_amdgcn_cvt_pkrtz(p2[2], p2[3]));
        B1.x = __builtin_bit_cast(unsigned int, __builtin_amdgcn_cvt_pkrtz(p3[0], p3[1]));
        B1.y = __builtin_bit_cast(unsigned int, __builtin_amdgcn_cvt_pkrtz(p3[2], p3[3]));
        *(uint2*)&pwA[0] = A0;
        *(uint2*)&pwA[8] = A1;
        *(uint2*)&pwB[0] = B0;
        *(uint2*)&pwB[8] = B1;
        f16x8 pfA = *(const f16x8*)((const f16*)&pbuf[w][0][0] + lrow * 40 + grp * 8);
        f16x8 pfB = *(const f16x8*)((const f16*)&pbuf[w][1][0] + lrow * 40 + grp * 8);

        // ---- PV: O^T[c][q] += H^T[c][k] P^T[k][q]; ones-row accumulates l ----
        accl = MFMA16(ones, pfA, accl);
        accl = MFMA16(ones, pfB, accl);
#pragma unroll
        for (int cb = 0; cb < 4; ++cb) {
            acc[cb] = MFMA16(haA[cb], pfA, acc[cb]);
            acc[cb] = MFMA16(haB[cb], pfB, acc[cb]);
        }
    }

    if (NSPLIT == 1) {
        const float rin = 1.f / accl[0];
        const float gm = gamma[0];
        const size_t qg = (size_t)b * 4096 + qrow;
#pragma unroll
        for (int cb = 0; cb < 4; ++cb)
#pragma unroll
            for (int r = 0; r < 4; ++r) {
                const int c = cb * 16 + grp * 4 + r;
                out[qg * 64 + c] = fmaf(gm, acc[cb][r] * rin, x[qg * 64 + c]);
            }
    } else {
        float* pob = po + ((size_t)(kc * 8 + b) * 4096 + qrow) * 64;
#pragma unroll
        for (int cb = 0; cb < 4; ++cb)
            *(f32x4*)(pob + cb * 16 + grp * 4) = acc[cb];
        if (lane < 16) {
            float* pm = pml + ((size_t)(kc * 8 + b) * 4096 + qrow) * 2;
            pm[0] = mrun;
            pm[1] = accl[0];
        }
    }
}

// ---------------- Kernel 3: split-K combine ----------------
__global__ __launch_bounds__(256) void combine_kernel(
    const float* __restrict__ po, const float* __restrict__ pml,
    const float* __restrict__ x, const float* __restrict__ gamma,
    float* __restrict__ out)
{
    const int gtid = blockIdx.x * 256 + threadIdx.x;   // 131072 threads, 16 ch each
    const int qg = gtid >> 2;                          // b*4096+n
    const int b  = qg >> 12;
    const int n  = qg & 4095;
    const int c0 = (gtid & 3) * 16;

    const float2 ml0 = *(const float2*)(pml + ((size_t)b * 4096 + n) * 2);
    const float2 ml1 = *(const float2*)(pml + ((size_t)(8 + b) * 4096 + n) * 2);
    const float M  = fmaxf(ml0.x, ml1.x);
    const float e0 = exp2f(ml0.x - M);
    const float e1 = exp2f(ml1.x - M);
    const float rin = gamma[0] / (e0 * ml0.y + e1 * ml1.y);
    const float a0 = e0 * rin, a1 = e1 * rin;

    const float4* q0 = (const float4*)(po + ((size_t)b * 4096 + n) * 64 + c0);
    const float4* q1 = (const float4*)(po + ((size_t)(8 + b) * 4096 + n) * 64 + c0);
    const float4* xq = (const float4*)(x + (size_t)qg * 64 + c0);
    float4* oq = (float4*)(out + (size_t)qg * 64 + c0);
#pragma unroll
    for (int j = 0; j < 4; ++j) {
        float4 v0 = q0[j], v1 = q1[j], xv = xq[j];
        float4 o;
        o.x = fmaf(a0, v0.x, fmaf(a1, v1.x, xv.x));
        o.y = fmaf(a0, v0.y, fmaf(a1, v1.y, xv.y));
        o.z = fmaf(a0, v0.z, fmaf(a1, v1.z, xv.z));
        o.w = fmaf(a0, v0.w, fmaf(a1, v1.w, xv.w));
        oq[j] = o;
    }
}

extern "C" void kernel_launch(void* const* d_in, const int* in_sizes, int n_in,
                              void* d_out, int out_size, void* d_ws, size_t ws_size,
                              hipStream_t stream) {
    const float* x     = (const float*)d_in[0];
    const float* Kf    = (const float*)d_in[1];
    const float* Kg    = (const float*)d_in[2];
    const float* Kh    = (const float*)d_in[3];
    const float* bf    = (const float*)d_in[4];
    const float* bg    = (const float*)d_in[5];
    const float* bh    = (const float*)d_in[6];
    const float* gamma = (const float*)d_in[7];
    float* out = (float*)d_out;

    f16* fO = (f16*)d_ws;                               // 512 KB
    f16* gO = (f16*)((char*)d_ws + (512 << 10));        // 512 KB
    f16* hT = (f16*)((char*)d_ws + (1 << 20));          // 4 MB
    float* po  = (float*)((char*)d_ws + (5 << 20));     // 16 MB (split-2 partial O)
    float* pml = (float*)((char*)d_ws + (21 << 20));    // 512 KB (m,l pairs)
    const size_t need = ((size_t)21 << 20) + ((size_t)1 << 19);

    hipLaunchKernelGGL(proj_kernel, dim3(512), dim3(256), 0, stream,
                       x, Kf, Kg, Kh, bf, bg, bh, fO, gO, hT);
    if (ws_size >= need) {
        hipLaunchKernelGGL((attn2_kernel<2>), dim3(1024), dim3(256), 0, stream,
                           fO, gO, hT, x, gamma, out, po, pml);
        hipLaunchKernelGGL(combine_kernel, dim3(512), dim3(256), 0, stream,
                           po, pml, x, gamma, out);
    } else {
        hipLaunchKernelGGL((attn2_kernel<1>), dim3(512), dim3(256), 0, stream,
                           fO, gO, hT, x, gamma, out, po, pml);
    }
}

// Round 3
// 89.448 us; speedup vs baseline: 1.8247x; 1.8247x over previous
//
#include <hip/hip_runtime.h>

typedef _Float16 f16;
typedef _Float16 f16x8 __attribute__((ext_vector_type(8)));
typedef float f32x4 __attribute__((ext_vector_type(4)));

#define LOG2E 1.44269504088896f
#define MFMA16(a, b, c) __builtin_amdgcn_mfma_f32_16x16x32_f16(a, b, c, 0, 0, 0)

static __device__ inline f16x8 f16x8_zero() {
    f16x8 v;
#pragma unroll
    for (int i = 0; i < 8; ++i) v[i] = (f16)0.f;
    return v;
}

// ---------------- Kernel 1: projections ----------------
// x: [B,4096,64] f32.  Outputs: fO [B*4096][8] f16, gO [B*4096][8] f16 (pre-scaled by log2e),
// hF: h in FRAGMENT-MAJOR layout so attention PV fragments are lane-contiguous:
//   hF flat index = b*262144 + t*4096 + cb*1024 + half*512 + lanegrp*128 + (c&15)*8 + (n&7)
//   where n = key pixel, t=n>>6, half=(n>>5)&1, lanegrp=(n>>3)&3, cb=c>>4.
// A PV fragment (t, cb, half) is then 64 lanes x 16B contiguous.
__global__ __launch_bounds__(256) void proj_kernel(
    const float* __restrict__ x, const float* __restrict__ Kf,
    const float* __restrict__ Kg, const float* __restrict__ Kh,
    const float* __restrict__ bf, const float* __restrict__ bg,
    const float* __restrict__ bh,
    f16* __restrict__ fO, f16* __restrict__ gO, f16* __restrict__ hF)
{
    __shared__ float KT[80 * 64];   // KT[c][d]: c<8 -> f, 8..15 -> g (scaled), 16..79 -> h
    __shared__ float bias[80];
    const int tid = threadIdx.x;

    for (int i = tid; i < 512; i += 256) {          // Kf/Kg are [64][8]
        int d = i >> 3, j = i & 7;
        KT[j * 64 + d] = Kf[i];
        KT[(8 + j) * 64 + d] = Kg[i] * LOG2E;
    }
    for (int i = tid; i < 4096; i += 256) {         // Kh is [64][64]
        int d = i >> 6, c = i & 63;
        KT[(16 + c) * 64 + d] = Kh[i];
    }
    if (tid < 8) { bias[tid] = bf[tid]; bias[8 + tid] = bg[tid] * LOG2E; }
    if (tid >= 16 && tid < 80) bias[tid] = bh[tid - 16];
    __syncthreads();

    const int quarter = tid >> 6;                   // wave id: which 20 output channels
    const int px = blockIdx.x * 64 + (tid & 63);    // pixel (b*4096 + n)
    const float4* xp = (const float4*)(x + (size_t)px * 64);
    float4 xr[16];
#pragma unroll
    for (int i = 0; i < 16; ++i) xr[i] = xp[i];

    float res[20];
    const int c0 = quarter * 20;
#pragma unroll
    for (int cc = 0; cc < 20; ++cc) {
        const int c = c0 + cc;
        float acc = bias[c];
        const float4* wv = (const float4*)(KT + c * 64);
#pragma unroll
        for (int i = 0; i < 16; ++i) {
            float4 w = wv[i];
            acc = fmaf(xr[i].x, w.x, acc);
            acc = fmaf(xr[i].y, w.y, acc);
            acc = fmaf(xr[i].z, w.z, acc);
            acc = fmaf(xr[i].w, w.w, acc);
        }
        res[cc] = acc;
    }

    const int b = px >> 12, n = px & 4095;
    const size_t hbase = (size_t)b * 262144
                       + (size_t)(n >> 6) * 4096 + (size_t)((n >> 5) & 1) * 512
                       + (size_t)((n >> 3) & 3) * 128 + (n & 7);
    if (quarter == 0) {
        f16x8 fv, gv;
#pragma unroll
        for (int j = 0; j < 8; ++j) { fv[j] = (f16)res[j]; gv[j] = (f16)res[8 + j]; }
        *(f16x8*)(fO + (size_t)px * 8) = fv;
        *(f16x8*)(gO + (size_t)px * 8) = gv;
#pragma unroll
        for (int cc = 16; cc < 20; ++cc) {
            const int hc = c0 + cc - 16;
            hF[hbase + (hc >> 4) * 1024 + (hc & 15) * 8] = (f16)res[cc];
        }
    } else {
#pragma unroll
        for (int cc = 0; cc < 20; ++cc) {
            const int hc = c0 + cc - 16;
            hF[hbase + (hc >> 4) * 1024 + (hc & 15) * 8] = (f16)res[cc];
        }
    }
}

// ---------------- Kernel 2: flash attention (split-K, barrier-free) ----------------
// NSPLIT blocks per 64-q tile, each covering 4096/NSPLIT keys. 4 waves x 16 q-rows.
// h fragments load directly from global in fragment-major layout: every load is
// a lane-contiguous 1KB dwordx4 (L1/L2 friendly). No __syncthreads anywhere;
// only LDS use is the tiny per-wave p-transpose.
// Swapped QK^T (S^T = F G^T) so q = lane&15; PV computes O^T = H^T P^T.
// l accumulated by a ones-row MFMA. Defer-max: rescale only when tile max
// exceeds running max by >8 (p <= 2^8, safe in f16).
template<int NSPLIT>
__global__ __launch_bounds__(256, 4) void attn3_kernel(
    const f16* __restrict__ fO, const f16* __restrict__ gO,
    const f16* __restrict__ hF, const float* __restrict__ x,
    const float* __restrict__ gamma, float* __restrict__ out,
    float* __restrict__ po, float* __restrict__ pml)
{
    __shared__ __align__(16) unsigned int pbuf[4][2][320];   // per-wave, stride 20 dwords

    const int tid  = threadIdx.x;
    const int w    = tid >> 6;
    const int lane = tid & 63;
    const int lrow = lane & 15;
    const int grp  = lane >> 4;

    const int b  = blockIdx.x & 7;
    const int kc = (NSPLIT == 2) ? ((blockIdx.x >> 3) & 1) : 0;
    const int qt = blockIdx.x >> ((NSPLIT == 2) ? 4 : 3);

    const int KEYS = 4096 / NSPLIT;
    const int NIT  = KEYS / 64;
    const int k0   = kc * KEYS;
    const int qrow = qt * 64 + w * 16 + lrow;     // this lane's query row

    const f16* fb = fO + (size_t)b * 32768;

    // B operand of QK: lanes<16 hold g[q][0..7], rest zero (K padded 8->32).
    // A-operand garbage at k>=8 is killed by these zeros, so f loads are unguarded.
    f16x8 gfrag = f16x8_zero();
    if (lane < 16) gfrag = *(const f16x8*)(gO + (size_t)b * 32768 + (size_t)qrow * 8);

    f16x8 ones;
#pragma unroll
    for (int i = 0; i < 8; ++i) ones[i] = (f16)1.f;

    f32x4 acc[4], accl;
#pragma unroll
    for (int cb = 0; cb < 4; ++cb)
#pragma unroll
        for (int r = 0; r < 4; ++r) acc[cb][r] = 0.f;
#pragma unroll
    for (int r = 0; r < 4; ++r) accl[r] = 0.f;

    // fragment-major h: per (tile, cb, half) one contiguous 1KB wave-load
    const f16* hp0 = hF + (size_t)b * 262144 + (size_t)(k0 >> 6) * 4096 + (size_t)lane * 8;
    const f16* fp  = fb + (size_t)(k0 + lrow) * 8;             // + t*512 + i*128

    float mrun = -1e30f;

    f16x8 faN[4];
#pragma unroll
    for (int i = 0; i < 4; ++i) faN[i] = *(const f16x8*)(fp + i * 128);

    for (int t = 0; t < NIT; ++t) {
        f16x8 fa[4];
#pragma unroll
        for (int i = 0; i < 4; ++i) fa[i] = faN[i];

        // issue all 8 h fragment loads early; softmax covers their latency
        const f16* hpt = hp0 + (size_t)t * 4096;
        f16x8 haA[4], haB[4];
#pragma unroll
        for (int cb = 0; cb < 4; ++cb) {
            haA[cb] = *(const f16x8*)(hpt + cb * 1024);
            haB[cb] = *(const f16x8*)(hpt + cb * 1024 + 512);
        }

        if (t + 1 < NIT) {                          // software-pipeline f fragments
            const f16* fpn = fp + (t + 1) * 512;
#pragma unroll
            for (int i = 0; i < 4; ++i) faN[i] = *(const f16x8*)(fpn + i * 128);
        }

        // ---- QK^T: S^T[key][q], keys t*64 + i*16 + grp*4 + r, q = lrow ----
        f32x4 zc; zc[0] = zc[1] = zc[2] = zc[3] = 0.f;
        f32x4 s0 = MFMA16(fa[0], gfrag, zc);
        f32x4 s1 = MFMA16(fa[1], gfrag, zc);
        f32x4 s2 = MFMA16(fa[2], gfrag, zc);
        f32x4 s3 = MFMA16(fa[3], gfrag, zc);

        // ---- online softmax (log2 units) ----
        float m8 = fmaxf(
            fmaxf(fmaxf(fmaxf(s0[0], s0[1]), fmaxf(s0[2], s0[3])),
                  fmaxf(fmaxf(s1[0], s1[1]), fmaxf(s1[2], s1[3]))),
            fmaxf(fmaxf(fmaxf(s2[0], s2[1]), fmaxf(s2[2], s2[3])),
                  fmaxf(fmaxf(s3[0], s3[1]), fmaxf(s3[2], s3[3]))));
        m8 = fmaxf(m8, __shfl_xor(m8, 16));
        m8 = fmaxf(m8, __shfl_xor(m8, 32));

        if (__any(m8 > mrun + 8.f)) {               // defer-max (T13)
            const float mnew = fmaxf(mrun, m8);
            const float sc = exp2f(mrun - mnew);
            mrun = mnew;
#pragma unroll
            for (int cb = 0; cb < 4; ++cb)
#pragma unroll
                for (int r = 0; r < 4; ++r) acc[cb][r] *= sc;
#pragma unroll
            for (int r = 0; r < 4; ++r) accl[r] *= sc;
        }

        f32x4 p0, p1, p2, p3;
#pragma unroll
        for (int r = 0; r < 4; ++r) {
            p0[r] = exp2f(s0[r] - mrun);
            p1[r] = exp2f(s1[r] - mrun);
            p2[r] = exp2f(s2[r] - mrun);
            p3[r] = exp2f(s3[r] - mrun);
        }

        // ---- pack p -> f16, per-wave LDS transpose ----
        unsigned int* pwA = &pbuf[w][0][lrow * 20 + 2 * grp];
        unsigned int* pwB = &pbuf[w][1][lrow * 20 + 2 * grp];
        uint2 A0, A1, B0, B1;
        A0.x = __builtin_bit_cast(unsigned int, __builtin_amdgcn_cvt_pkrtz(p0[0], p0[1]));
        A0.y = __builtin_bit_cast(unsigned int, __builtin_amdgcn_cvt_pkrtz(p0[2], p0[3]));
        A1.x = __builtin_bit_cast(unsigned int, __builtin_amdgcn_cvt_pkrtz(p1[0], p1[1]));
        A1.y = __builtin_bit_cast(unsigned int, __builtin_amdgcn_cvt_pkrtz(p1[2], p1[3]));
        B0.x = __builtin_bit_cast(unsigned int, __builtin_amdgcn_cvt_pkrtz(p2[0], p2[1]));
        B0.y = __builtin_bit_cast(unsigned int, __builtin_amdgcn_cvt_pkrtz(p2[2], p2[3]));
        B1.x = __builtin_bit_cast(unsigned int, __builtin_amdgcn_cvt_pkrtz(p3[0], p3[1]));
        B1.y = __builtin_bit_cast(unsigned int, __builtin_amdgcn_cvt_pkrtz(p3[2], p3[3]));
        *(uint2*)&pwA[0] = A0;
        *(uint2*)&pwA[8] = A1;
        *(uint2*)&pwB[0] = B0;
        *(uint2*)&pwB[8] = B1;
        f16x8 pfA = *(const f16x8*)((const f16*)&pbuf[w][0][0] + lrow * 40 + grp * 8);
        f16x8 pfB = *(const f16x8*)((const f16*)&pbuf[w][1][0] + lrow * 40 + grp * 8);

        // ---- PV: O^T[c][q] += H^T[c][k] P^T[k][q]; ones-row accumulates l ----
        accl = MFMA16(ones, pfA, accl);
        accl = MFMA16(ones, pfB, accl);
#pragma unroll
        for (int cb = 0; cb < 4; ++cb) {
            acc[cb] = MFMA16(haA[cb], pfA, acc[cb]);
            acc[cb] = MFMA16(haB[cb], pfB, acc[cb]);
        }
    }

    if (NSPLIT == 1) {
        const float rin = 1.f / accl[0];
        const float gm = gamma[0];
        const size_t qg = (size_t)b * 4096 + qrow;
#pragma unroll
        for (int cb = 0; cb < 4; ++cb)
#pragma unroll
            for (int r = 0; r < 4; ++r) {
                const int c = cb * 16 + grp * 4 + r;
                out[qg * 64 + c] = fmaf(gm, acc[cb][r] * rin, x[qg * 64 + c]);
            }
    } else {
        float* pob = po + ((size_t)(kc * 8 + b) * 4096 + qrow) * 64;
#pragma unroll
        for (int cb = 0; cb < 4; ++cb)
            *(f32x4*)(pob + cb * 16 + grp * 4) = acc[cb];
        if (lane < 16) {
            float* pm = pml + ((size_t)(kc * 8 + b) * 4096 + qrow) * 2;
            pm[0] = mrun;
            pm[1] = accl[0];
        }
    }
}

// ---------------- Kernel 3: split-K combine ----------------
__global__ __launch_bounds__(256) void combine_kernel(
    const float* __restrict__ po, const float* __restrict__ pml,
    const float* __restrict__ x, const float* __restrict__ gamma,
    float* __restrict__ out)
{
    const int gtid = blockIdx.x * 256 + threadIdx.x;   // 131072 threads, 16 ch each
    const int qg = gtid >> 2;                          // b*4096+n
    const int b  = qg >> 12;
    const int n  = qg & 4095;
    const int c0 = (gtid & 3) * 16;

    const float2 ml0 = *(const float2*)(pml + ((size_t)b * 4096 + n) * 2);
    const float2 ml1 = *(const float2*)(pml + ((size_t)(8 + b) * 4096 + n) * 2);
    const float M  = fmaxf(ml0.x, ml1.x);
    const float e0 = exp2f(ml0.x - M);
    const float e1 = exp2f(ml1.x - M);
    const float rin = gamma[0] / (e0 * ml0.y + e1 * ml1.y);
    const float a0 = e0 * rin, a1 = e1 * rin;

    const float4* q0 = (const float4*)(po + ((size_t)b * 4096 + n) * 64 + c0);
    const float4* q1 = (const float4*)(po + ((size_t)(8 + b) * 4096 + n) * 64 + c0);
    const float4* xq = (const float4*)(x + (size_t)qg * 64 + c0);
    float4* oq = (float4*)(out + (size_t)qg * 64 + c0);
#pragma unroll
    for (int j = 0; j < 4; ++j) {
        float4 v0 = q0[j], v1 = q1[j], xv = xq[j];
        float4 o;
        o.x = fmaf(a0, v0.x, fmaf(a1, v1.x, xv.x));
        o.y = fmaf(a0, v0.y, fmaf(a1, v1.y, xv.y));
        o.z = fmaf(a0, v0.z, fmaf(a1, v1.z, xv.z));
        o.w = fmaf(a0, v0.w, fmaf(a1, v1.w, xv.w));
        oq[j] = o;
    }
}

extern "C" void kernel_launch(void* const* d_in, const int* in_sizes, int n_in,
                              void* d_out, int out_size, void* d_ws, size_t ws_size,
                              hipStream_t stream) {
    const float* x     = (const float*)d_in[0];
    const float* Kf    = (const float*)d_in[1];
    const float* Kg    = (const float*)d_in[2];
    const float* Kh    = (const float*)d_in[3];
    const float* bf    = (const float*)d_in[4];
    const float* bg    = (const float*)d_in[5];
    const float* bh    = (const float*)d_in[6];
    const float* gamma = (const float*)d_in[7];
    float* out = (float*)d_out;

    f16* fO = (f16*)d_ws;                               // 512 KB
    f16* gO = (f16*)((char*)d_ws + (512 << 10));        // 512 KB
    f16* hF = (f16*)((char*)d_ws + (1 << 20));          // 4 MB (fragment-major h)
    float* po  = (float*)((char*)d_ws + (5 << 20));     // 16 MB (split-2 partial O)
    float* pml = (float*)((char*)d_ws + (21 << 20));    // 512 KB (m,l pairs)
    const size_t need = ((size_t)21 << 20) + ((size_t)1 << 19);

    hipLaunchKernelGGL(proj_kernel, dim3(512), dim3(256), 0, stream,
                       x, Kf, Kg, Kh, bf, bg, bh, fO, gO, hF);
    if (ws_size >= need) {
        hipLaunchKernelGGL((attn3_kernel<2>), dim3(1024), dim3(256), 0, stream,
                           fO, gO, hF, x, gamma, out, po, pml);
        hipLaunchKernelGGL(combine_kernel, dim3(512), dim3(256), 0, stream,
                           po, pml, x, gamma, out);
    } else {
        hipLaunchKernelGGL((attn3_kernel<1>), dim3(512), dim3(256), 0, stream,
                           fO, gO, hF, x, gamma, out, po, pml);
    }
}

// Round 4
// 80.793 us; speedup vs baseline: 2.0202x; 1.1071x over previous
//
#include <hip/hip_runtime.h>

typedef _Float16 f16;
typedef _Float16 f16x2 __attribute__((ext_vector_type(2)));
typedef _Float16 f16x8 __attribute__((ext_vector_type(8)));
typedef float f32x4 __attribute__((ext_vector_type(4)));
typedef float f32x16 __attribute__((ext_vector_type(16)));
typedef unsigned int u32x4 __attribute__((ext_vector_type(4)));

#define LOG2E 1.44269504088896f
#define MFMA32(a, b, c) __builtin_amdgcn_mfma_f32_32x32x16_f16(a, b, c, 0, 0, 0)

static __device__ inline f16x8 f16x8_zero() {
    f16x8 v;
#pragma unroll
    for (int i = 0; i < 8; ++i) v[i] = (f16)0.f;
    return v;
}

// v_permlane32_swap_b32: a' = [a.row0 | b.row0], b' = [a.row1 | b.row1]
static __device__ inline void perm32swap(unsigned int& a, unsigned int& b) {
    asm("v_permlane32_swap_b32 %0, %1" : "+v"(a), "+v"(b));
}

// ---------------- Kernel 1: projections ----------------
// Outputs: fO/gO [B*4096][8] f16 (g pre-scaled by log2e), and h in 32x32x16
// FRAGMENT-MAJOR layout hF[b][kt=n>>4][cb=c>>5][lane][r]:
//   lane = (c&31) + 32*((n>>3)&1), r = n&7  ->  each PV A-fragment is one
//   lane-contiguous 1KB wave load / linear LDS-free stream.
__global__ __launch_bounds__(256) void proj_kernel(
    const float* __restrict__ x, const float* __restrict__ Kf,
    const float* __restrict__ Kg, const float* __restrict__ Kh,
    const float* __restrict__ bf, const float* __restrict__ bg,
    const float* __restrict__ bh,
    f16* __restrict__ fO, f16* __restrict__ gO, f16* __restrict__ hF)
{
    __shared__ float KT[80 * 64];   // KT[c][d]: c<8 -> f, 8..15 -> g (scaled), 16..79 -> h
    __shared__ float bias[80];
    const int tid = threadIdx.x;

    for (int i = tid; i < 512; i += 256) {          // Kf/Kg are [64][8]
        int d = i >> 3, j = i & 7;
        KT[j * 64 + d] = Kf[i];
        KT[(8 + j) * 64 + d] = Kg[i] * LOG2E;
    }
    for (int i = tid; i < 4096; i += 256) {         // Kh is [64][64]
        int d = i >> 6, c = i & 63;
        KT[(16 + c) * 64 + d] = Kh[i];
    }
    if (tid < 8) { bias[tid] = bf[tid]; bias[8 + tid] = bg[tid] * LOG2E; }
    if (tid >= 16 && tid < 80) bias[tid] = bh[tid - 16];
    __syncthreads();

    const int quarter = tid >> 6;                   // wave id: which 20 output channels
    const int px = blockIdx.x * 64 + (tid & 63);    // pixel (b*4096 + n)
    const float4* xp = (const float4*)(x + (size_t)px * 64);
    float4 xr[16];
#pragma unroll
    for (int i = 0; i < 16; ++i) xr[i] = xp[i];

    float res[20];
    const int c0 = quarter * 20;
#pragma unroll
    for (int cc = 0; cc < 20; ++cc) {
        const int c = c0 + cc;
        float acc = bias[c];
        const float4* wv = (const float4*)(KT + c * 64);
#pragma unroll
        for (int i = 0; i < 16; ++i) {
            float4 w = wv[i];
            acc = fmaf(xr[i].x, w.x, acc);
            acc = fmaf(xr[i].y, w.y, acc);
            acc = fmaf(xr[i].z, w.z, acc);
            acc = fmaf(xr[i].w, w.w, acc);
        }
        res[cc] = acc;
    }

    const int b = px >> 12, n = px & 4095;
    const size_t hbase = (size_t)b * 262144 + (size_t)(n >> 4) * 1024
                       + (size_t)((n >> 3) & 1) * 256 + (n & 7);
    if (quarter == 0) {
        f16x8 fv, gv;
#pragma unroll
        for (int j = 0; j < 8; ++j) { fv[j] = (f16)res[j]; gv[j] = (f16)res[8 + j]; }
        *(f16x8*)(fO + (size_t)px * 8) = fv;
        *(f16x8*)(gO + (size_t)px * 8) = gv;
#pragma unroll
        for (int cc = 16; cc < 20; ++cc) {
            const int hc = c0 + cc - 16;
            hF[hbase + (hc >> 5) * 512 + (hc & 31) * 8] = (f16)res[cc];
        }
    } else {
#pragma unroll
        for (int cc = 0; cc < 20; ++cc) {
            const int hc = c0 + cc - 16;
            hF[hbase + (hc >> 5) * 512 + (hc & 31) * 8] = (f16)res[cc];
        }
    }
}

// ---------------- Kernel 2: flash attention (32x32 MFMA, split-K, LDS-free) ----
// Block = 4 waves x 32 q-rows = 128 q. Swapped QK^T via mfma_f32_32x32x16_f16
// (S^T: col=q=lane&31, row=key=(reg&3)+8*(reg>>2)+4*(lane>>5)). P-fragments for
// PV are assembled IN-REGISTER via cvt_pkrtz + v_permlane32_swap_b32 (no LDS).
// PV: O^T = H^T P^T, 2 c-blocks of 32. l via v_pk_add_f16 tree. Defer-max.
template<int NSPLIT>
__global__ __launch_bounds__(256, 3) void attn4_kernel(
    const f16* __restrict__ fO, const f16* __restrict__ gO,
    const f16* __restrict__ hF, const float* __restrict__ x,
    const float* __restrict__ gamma, float* __restrict__ out,
    float* __restrict__ po, float* __restrict__ pml)
{
    const int tid  = threadIdx.x;
    const int w    = tid >> 6;
    const int lane = tid & 63;
    const int q5   = lane & 31;
    const int hi   = lane >> 5;

    const int b = blockIdx.x & 7;
    int kc, qt;
    if (NSPLIT == 4)      { kc = (blockIdx.x >> 3) & 3; qt = blockIdx.x >> 5; }
    else if (NSPLIT == 2) { kc = (blockIdx.x >> 3) & 1; qt = blockIdx.x >> 4; }
    else                  { kc = 0;                     qt = blockIdx.x >> 3; }

    const int KEYS = 4096 / NSPLIT;
    const int NIT  = KEYS / 64;
    const int k0   = kc * KEYS;
    const int qrow = qt * 128 + w * 32 + q5;

    const f16* fb = fO + (size_t)b * 32768;
    const f16* hb = hF + (size_t)b * 262144;

    // QK B operand: lanes<32 hold g[q][0..7] (k=0..7); lanes>=32 zero (K pad 8->16).
    f16x8 gfrag = f16x8_zero();
    if (lane < 32) gfrag = *(const f16x8*)(gO + (size_t)b * 32768 + (size_t)qrow * 8);

    f32x16 acc0, acc1;
#pragma unroll
    for (int i = 0; i < 16; ++i) { acc0[i] = 0.f; acc1[i] = 0.f; }
    float mrun = -1e30f, lpart = 0.f;

    const f16* fpk = fb + (size_t)k0 * 8;
    const f16* hpk = hb + (size_t)k0 * 64 + (size_t)lane * 8;

    f16x8 faA = *(const f16x8*)(fpk + q5 * 8);          // keys 0..31 (A rows)
    f16x8 faB = *(const f16x8*)(fpk + q5 * 8 + 256);    // keys 32..63

    for (int t = 0; t < NIT; ++t) {
        // ---- issue h fragment loads early (8 x 1KB lane-contiguous) ----
        const f16* hpt = hpk + (size_t)t * 4096;
        f16x8 ha[8];
#pragma unroll
        for (int kk = 0; kk < 4; ++kk) {
            ha[kk * 2 + 0] = *(const f16x8*)(hpt + kk * 1024);
            ha[kk * 2 + 1] = *(const f16x8*)(hpt + kk * 1024 + 512);
        }
        const f16x8 fa0 = faA, fa1 = faB;
        if (t + 1 < NIT) {                               // prefetch next f
            const f16* fpn = fpk + ((t + 1) * 64 + q5) * 8;
            faA = *(const f16x8*)(fpn);
            faB = *(const f16x8*)(fpn + 256);
        }

        // ---- QK^T: s[reg] = S[key][q], q = lane&31 ----
        f32x16 zc;
#pragma unroll
        for (int i = 0; i < 16; ++i) zc[i] = 0.f;
        f32x16 s0 = MFMA32(fa0, gfrag, zc);
        f32x16 s1 = MFMA32(fa1, gfrag, zc);

        // ---- online softmax (log2 units): tree max over 32, then cross-half ----
        f32x16 mt;
#pragma unroll
        for (int i = 0; i < 16; ++i) mt[i] = fmaxf(s0[i], s1[i]);
#pragma unroll
        for (int st = 8; st >= 1; st >>= 1)
#pragma unroll
            for (int i = 0; i < st; ++i) mt[i] = fmaxf(mt[i], mt[i + st]);
        float m8 = fmaxf(mt[0], __shfl_xor(mt[0], 32));

        if (__any(m8 > mrun + 8.f)) {                    // defer-max (T13)
            const float mnew = fmaxf(mrun, m8);
            const float sc = exp2f(mrun - mnew);
            mrun = mnew;
#pragma unroll
            for (int i = 0; i < 16; ++i) { acc0[i] *= sc; acc1[i] *= sc; }
            lpart *= sc;
        }

        f32x16 p0, p1;
#pragma unroll
        for (int i = 0; i < 16; ++i) {
            p0[i] = exp2f(s0[i] - mrun);
            p1[i] = exp2f(s1[i] - mrun);
        }

        // ---- pack to f16 pairs (consecutive regs = consecutive keys) ----
        unsigned int wr[16];
#pragma unroll
        for (int i = 0; i < 8; ++i) {
            wr[i]     = __builtin_bit_cast(unsigned int, __builtin_amdgcn_cvt_pkrtz(p0[2 * i], p0[2 * i + 1]));
            wr[8 + i] = __builtin_bit_cast(unsigned int, __builtin_amdgcn_cvt_pkrtz(p1[2 * i], p1[2 * i + 1]));
        }

        // ---- l partial via v_pk_add_f16 tree over own 32 keys ----
        {
            f16x2 s8[8];
#pragma unroll
            for (int i = 0; i < 8; ++i)
                s8[i] = __builtin_bit_cast(f16x2, wr[i]) + __builtin_bit_cast(f16x2, wr[8 + i]);
#pragma unroll
            for (int st = 4; st >= 1; st >>= 1)
#pragma unroll
                for (int i = 0; i < st; ++i) s8[i] = s8[i] + s8[i + st];
            lpart += (float)s8[0][0] + (float)s8[0][1];
        }

        // ---- assemble PV B-fragments in-register (T12): 8 permlane32_swap ----
        perm32swap(wr[0], wr[2]);   perm32swap(wr[1], wr[3]);    // keys  0..15
        perm32swap(wr[4], wr[6]);   perm32swap(wr[5], wr[7]);    // keys 16..31
        perm32swap(wr[8], wr[10]);  perm32swap(wr[9], wr[11]);   // keys 32..47
        perm32swap(wr[12], wr[14]); perm32swap(wr[13], wr[15]);  // keys 48..63

        // ---- PV: O^T[c][q] += H^T[c][k] P^T[k][q] ----
#pragma unroll
        for (int kk = 0; kk < 4; ++kk) {
            u32x4 tv;
            tv[0] = wr[kk * 4 + 0]; tv[1] = wr[kk * 4 + 1];
            tv[2] = wr[kk * 4 + 2]; tv[3] = wr[kk * 4 + 3];
            const f16x8 pf = __builtin_bit_cast(f16x8, tv);
            acc0 = MFMA32(ha[kk * 2 + 0], pf, acc0);
            acc1 = MFMA32(ha[kk * 2 + 1], pf, acc1);
        }
    }

    lpart += __shfl_xor(lpart, 32);

    if (NSPLIT == 1) {
        const float rin = 1.f / lpart;
        const float gm = gamma[0];
        const size_t qg = (size_t)b * 4096 + qrow;
#pragma unroll
        for (int cb = 0; cb < 2; ++cb)
#pragma unroll
            for (int r = 0; r < 4; ++r) {
                const size_t o = qg * 64 + cb * 32 + r * 8 + hi * 4;
                f32x4 v;
#pragma unroll
                for (int j = 0; j < 4; ++j) {
                    const float a = (cb == 0) ? acc0[4 * r + j] : acc1[4 * r + j];
                    v[j] = fmaf(gm, a * rin, x[o + j]);
                }
                *(f32x4*)(out + o) = v;
            }
    } else {
        float* pob = po + (size_t)((kc * 8 + b) * 128 + qt * 4 + w) * 2048;
#pragma unroll
        for (int cb = 0; cb < 2; ++cb)
#pragma unroll
            for (int r = 0; r < 4; ++r) {
                f32x4 v;
#pragma unroll
                for (int j = 0; j < 4; ++j)
                    v[j] = (cb == 0) ? acc0[4 * r + j] : acc1[4 * r + j];
                *(f32x4*)(pob + (cb * 4 + r) * 256 + lane * 4) = v;
            }
        if (lane < 32) {
            float2 ml; ml.x = mrun; ml.y = lpart;
            *(float2*)(pml + ((size_t)(kc * 8 + b) * 4096 + qrow) * 2) = ml;
        }
    }
}

// ---------------- Kernel 3: split-K combine ----------------
template<int NS>
__global__ __launch_bounds__(256) void combine_kernel(
    const float* __restrict__ po, const float* __restrict__ pml,
    const float* __restrict__ x, const float* __restrict__ gamma,
    float* __restrict__ out)
{
    const int t    = blockIdx.x * 256 + threadIdx.x;    // 524288 threads
    const int lane = t & 63;
    const int r    = (t >> 6) & 3;
    const int cb   = (t >> 8) & 1;
    const int w    = (t >> 9) & 3;
    const int qt   = (t >> 11) & 31;
    const int b    = (t >> 16) & 7;
    const int q    = qt * 128 + w * 32 + (lane & 31);
    const int c    = cb * 32 + r * 8 + (lane >> 5) * 4;

    float m[NS], l[NS];
    float M = -1e30f;
#pragma unroll
    for (int kc = 0; kc < NS; ++kc) {
        const float2 ml = *(const float2*)(pml + ((size_t)(kc * 8 + b) * 4096 + q) * 2);
        m[kc] = ml.x; l[kc] = ml.y;
        M = fmaxf(M, ml.x);
    }
    float denom = 0.f;
    f32x4 num;
#pragma unroll
    for (int j = 0; j < 4; ++j) num[j] = 0.f;
#pragma unroll
    for (int kc = 0; kc < NS; ++kc) {
        const float e = exp2f(m[kc] - M);
        denom = fmaf(e, l[kc], denom);
        const f32x4 v = *(const f32x4*)(po + (size_t)((kc * 8 + b) * 128 + qt * 4 + w) * 2048
                                           + (cb * 4 + r) * 256 + lane * 4);
#pragma unroll
        for (int j = 0; j < 4; ++j) num[j] = fmaf(e, v[j], num[j]);
    }
    const float sc = gamma[0] / denom;
    const size_t o = ((size_t)b * 4096 + q) * 64 + c;
    const f32x4 xv = *(const f32x4*)(x + o);
    f32x4 ov;
#pragma unroll
    for (int j = 0; j < 4; ++j) ov[j] = fmaf(sc, num[j], xv[j]);
    *(f32x4*)(out + o) = ov;
}

extern "C" void kernel_launch(void* const* d_in, const int* in_sizes, int n_in,
                              void* d_out, int out_size, void* d_ws, size_t ws_size,
                              hipStream_t stream) {
    const float* x     = (const float*)d_in[0];
    const float* Kf    = (const float*)d_in[1];
    const float* Kg    = (const float*)d_in[2];
    const float* Kh    = (const float*)d_in[3];
    const float* bf    = (const float*)d_in[4];
    const float* bg    = (const float*)d_in[5];
    const float* bh    = (const float*)d_in[6];
    const float* gamma = (const float*)d_in[7];
    float* out = (float*)d_out;

    f16* fO = (f16*)d_ws;                               // 512 KB
    f16* gO = (f16*)((char*)d_ws + (512 << 10));        // 512 KB
    f16* hF = (f16*)((char*)d_ws + (1 << 20));          // 4 MB (fragment-major h)
    float* po = (float*)((char*)d_ws + (5 << 20));      // NSPLIT*8 MB partial O

    const size_t need4 = ((size_t)5 << 20) + ((size_t)32 << 20) + ((size_t)1 << 20);
    const size_t need2 = ((size_t)5 << 20) + ((size_t)16 << 20) + ((size_t)1 << 19);

    hipLaunchKernelGGL(proj_kernel, dim3(512), dim3(256), 0, stream,
                       x, Kf, Kg, Kh, bf, bg, bh, fO, gO, hF);
    if (ws_size >= need4) {
        float* pml = (float*)((char*)d_ws + (37u << 20));
        hipLaunchKernelGGL((attn4_kernel<4>), dim3(1024), dim3(256), 0, stream,
                           fO, gO, hF, x, gamma, out, po, pml);
        hipLaunchKernelGGL((combine_kernel<4>), dim3(2048), dim3(256), 0, stream,
                           po, pml, x, gamma, out);
    } else if (ws_size >= need2) {
        float* pml = (float*)((char*)d_ws + (21u << 20));
        hipLaunchKernelGGL((attn4_kernel<2>), dim3(512), dim3(256), 0, stream,
                           fO, gO, hF, x, gamma, out, po, pml);
        hipLaunchKernelGGL((combine_kernel<2>), dim3(2048), dim3(256), 0, stream,
                           po, pml, x, gamma, out);
    } else {
        hipLaunchKernelGGL((attn4_kernel<1>), dim3(256), dim3(256), 0, stream,
                           fO, gO, hF, x, gamma, out, po, (float*)po);
    }
}